// Round 5
// baseline (72.476 us; speedup 1.0000x reference)
//
#include <hip/hip_runtime.h>

#define NUM_SLICE 32

// Problem constants (fixed by setup_inputs)
constexpr int Bc = 8;
constexpr int Cc = 128;
constexpr int Nc = 65536;

// Tiling: each block owns one (chunk, batch) and ALL 128 channels, so the
// slice indices are read once and held in registers across the channel loop.
constexpr int THREADS = 512;
constexpr int CHUNK   = 1024;             // points per block
constexpr int PPT     = CHUNK / THREADS;  // 2 points per thread (float2 loads)
constexpr int NCHUNK  = Nc / CHUNK;       // 64 -> grid 64x8 = 512 blocks
constexpr int NREP    = 2;                // lane-parity replicas for LDS atomics
constexpr int LD      = 33;               // acc[(c*NREP+rep)*LD + s]; bank=(2c+rep+s)%32
constexpr int OUT_PER_B = Cc * NUM_SLICE; // 4096

typedef unsigned int u32;
typedef uint4 u32x4;

__global__ __launch_bounds__(THREADS) void slice_pool_partial(
    const float* __restrict__ in,   // [B, C, N]
    const int*   __restrict__ idx,  // [B, N]
    u32* __restrict__ ws)           // [NCHUNK*Bc][4096] partial maxima (>=0 bits)
{
    __shared__ u32 acc[Cc * NREP * LD];   // 33 KB

    const int t = threadIdx.x;
    for (int i = t; i < Cc * NREP * LD; i += THREADS) acc[i] = 0u;
    __syncthreads();

    const int chunk = blockIdx.x;         // 0..63
    const int b     = blockIdx.y;         // 0..7
    const int n0    = chunk * CHUNK;

    // Two slice indices per thread, read once, live in registers for all 128 c.
    const int2 iv = *(const int2*)(idx + (size_t)b * Nc + n0 + 2 * t);
    const int roff = (t & 1) * LD;        // replica offset
    const int s0 = roff + iv.x;
    const int s1 = roff + iv.y;

    const float* __restrict__ inb = in + (size_t)b * Cc * Nc + n0 + 2 * t;

    #pragma unroll 8
    for (int c = 0; c < Cc; ++c) {
        const float2 v = *(const float2*)(inb + (size_t)c * Nc);
        // fmax(x,0)==0 bits iff x<=0: no-op vs zero-initialized acc -> skip.
        const u32 bx = __float_as_uint(fmaxf(v.x, 0.0f));
        const u32 by = __float_as_uint(fmaxf(v.y, 0.0f));
        const int base = c * (NREP * LD);
        if (bx) atomicMax(&acc[base + s0], bx);
        if (by) atomicMax(&acc[base + s1], by);
    }
    __syncthreads();

    // Merge replicas, plain-store partials (no global atomics, no init needed).
    u32* __restrict__ wsb = ws + ((size_t)chunk * Bc + b) * OUT_PER_B;
    for (int i = t; i < OUT_PER_B; i += THREADS) {
        const int c = i >> 5, s = i & 31;
        const u32 v0 = acc[(c * NREP + 0) * LD + s];
        const u32 v1 = acc[(c * NREP + 1) * LD + s];
        wsb[i] = v0 > v1 ? v0 : v1;
    }
}

__global__ __launch_bounds__(256) void slice_pool_reduce(
    const u32* __restrict__ ws,     // [NCHUNK*Bc][4096]
    u32* __restrict__ out)          // [Bc][4096]
{
    // One thread per 4 outputs: 8192 threads = 32 blocks x 256.
    const int gid = blockIdx.x * blockDim.x + threadIdx.x;
    const int b  = gid >> 10;             // 1024 uint4 per batch
    const int i4 = gid & 1023;

    const u32x4* __restrict__ w4 = (const u32x4*)ws;
    u32x4 m = {0u, 0u, 0u, 0u};
    #pragma unroll 16
    for (int chunk = 0; chunk < NCHUNK; ++chunk) {
        const u32x4 v = w4[((size_t)chunk * Bc + b) * (OUT_PER_B / 4) + i4];
        m.x = v.x > m.x ? v.x : m.x;
        m.y = v.y > m.y ? v.y : m.y;
        m.z = v.z > m.z ? v.z : m.z;
        m.w = v.w > m.w ? v.w : m.w;
    }
    ((u32x4*)out)[(size_t)b * (OUT_PER_B / 4) + i4] = m;  // covers poison
}

extern "C" void kernel_launch(void* const* d_in, const int* in_sizes, int n_in,
                              void* d_out, int out_size, void* d_ws, size_t ws_size,
                              hipStream_t stream) {
    const float* in  = (const float*)d_in[0];   // [8,128,65536,1] f32
    const int*   idx = (const int*)  d_in[1];   // [8,65536] i32
    u32* ws  = (u32*)d_ws;                      // 512 * 16 KB = 8 MB partials
    u32* out = (u32*)d_out;                     // [8,128,32,1] f32 (as >=0 bits)

    dim3 grid1(NCHUNK, Bc);                     // (64, 8) = 512 blocks
    slice_pool_partial<<<grid1, THREADS, 0, stream>>>(in, idx, ws);

    slice_pool_reduce<<<32, 256, 0, stream>>>(ws, out);
}

// Round 6
// 53.332 us; speedup vs baseline: 1.3590x; 1.3590x over previous
//
#include <hip/hip_runtime.h>

#define NUM_SLICE 32

// Problem constants (fixed by setup_inputs)
constexpr int Bc = 8;
constexpr int Cc = 128;
constexpr int Nc = 65536;

// Tiling: R2 structure, but 2x blocks (8 blocks/CU = 32 waves/CU) to maximize
// outstanding HBM loads. Single-variable change vs the 54.7us R2/R3 kernel.
constexpr int CPB     = 8;     // channels per block
constexpr int CHUNK   = 4096;  // points (n) per block
constexpr int THREADS = 256;
constexpr int PTS_PER_ITER = THREADS * 4;      // 1024 points / iter (float4)
constexpr int NITER   = CHUNK / PTS_PER_ITER;  // 4
constexpr int ACC_LD  = 33;    // padded stride: bank(c*33+s) = (c+s)%32
constexpr int NREP    = 2;     // replicas by lane parity: halves same-addr passes

typedef float f32x4 __attribute__((ext_vector_type(4)));
typedef int   i32x4 __attribute__((ext_vector_type(4)));

__global__ __launch_bounds__(THREADS) void init_out_kernel(float* out, int n) {
    int i = blockIdx.x * blockDim.x + threadIdx.x;
    if (i < n) out[i] = 0.0f;
}

__global__ __launch_bounds__(THREADS) void slice_pool_kernel(
    const float* __restrict__ in,       // [B, C, N]
    const int*   __restrict__ idx,      // [B, N], values in [0, 32)
    unsigned int* __restrict__ out)     // [B, C, 32] as uint bits (all >= 0)
{
    __shared__ unsigned int acc[NREP][CPB * ACC_LD];

    const int t = threadIdx.x;
    for (int i = t; i < NREP * CPB * ACC_LD; i += THREADS)
        (&acc[0][0])[i] = 0u;
    __syncthreads();

    const int chunk = blockIdx.x;           // 0..15
    const int cg    = blockIdx.y;           // 0..15
    const int b     = blockIdx.z;           // 0..7
    const int c0    = cg * CPB;
    const int n0    = chunk * CHUNK;
    const int rep   = t & 1;                // lane-parity replica

    const i32x4* __restrict__ idx4   = (const i32x4*)(idx + (size_t)b * Nc + n0);
    const float* __restrict__ inbase = in + ((size_t)b * Cc + c0) * Nc + n0;

    unsigned int* __restrict__ accr = acc[rep];

    #pragma unroll 2
    for (int p = 0; p < NITER; ++p) {
        const int e    = p * THREADS + t;  // int4 slot within chunk
        const i32x4 iv = idx4[e];
        const int off  = e * 4;            // element offset within chunk
        #pragma unroll
        for (int c = 0; c < CPB; ++c) {
            const f32x4 v = *(const f32x4*)(inbase + (size_t)c * Nc + off);
            const int base = c * ACC_LD;
            // fmax(x,0) == 0 bits iff x <= 0: those atomics are no-ops vs the
            // zero-initialized accumulator -> skip (halves active lanes).
            const unsigned int bx = __float_as_uint(fmaxf(v[0], 0.0f));
            const unsigned int by = __float_as_uint(fmaxf(v[1], 0.0f));
            const unsigned int bz = __float_as_uint(fmaxf(v[2], 0.0f));
            const unsigned int bw = __float_as_uint(fmaxf(v[3], 0.0f));
            if (bx) atomicMax(&accr[base + iv[0]], bx);
            if (by) atomicMax(&accr[base + iv[1]], by);
            if (bz) atomicMax(&accr[base + iv[2]], bz);
            if (bw) atomicMax(&accr[base + iv[3]], bw);
        }
    }
    __syncthreads();

    // Epilogue: one thread per (channel, slice); merge replicas -> global max
    if (t < CPB * NUM_SLICE) {
        const int c = t >> 5;
        const int s = t & 31;
        unsigned int v = acc[0][c * ACC_LD + s];
        const unsigned int v1 = acc[1][c * ACC_LD + s];
        v = v > v1 ? v : v1;
        if (v != 0u) {
            atomicMax(&out[(((size_t)b * Cc) + c0 + c) * NUM_SLICE + s], v);
        }
    }
}

extern "C" void kernel_launch(void* const* d_in, const int* in_sizes, int n_in,
                              void* d_out, int out_size, void* d_ws, size_t ws_size,
                              hipStream_t stream) {
    const float* in  = (const float*)d_in[0];   // [8,128,65536,1] f32
    const int*   idx = (const int*)  d_in[1];   // [8,65536] i32
    float* out = (float*)d_out;                 // [8,128,32,1] f32

    // Zero the output every launch (harness poisons d_out, never re-poisons).
    const int n_out = Bc * Cc * NUM_SLICE;      // 32768
    init_out_kernel<<<(n_out + THREADS - 1) / THREADS, THREADS, 0, stream>>>(out, n_out);

    dim3 grid(Nc / CHUNK, Cc / CPB, Bc);        // (16, 16, 8) = 2048 blocks
    slice_pool_kernel<<<grid, THREADS, 0, stream>>>(in, idx, (unsigned int*)out);
}